// Round 9
// baseline (233.645 us; speedup 1.0000x reference)
//
#include <hip/hip_runtime.h>
#include <hip/hip_bf16.h>
#include <string.h>

// GRU recommender, R9: B=32768, T=64, H=16, vocab=3.
// COOPERATIVE 2-WAVE blocks: 1024 blocks x 128 thr (2 waves) x 32 samples.
// 2048 waves -> 2 waves/SIMD (R8 had 1 => zero TLP; its 1537cyc/step wall
// was ~2x its issue estimate = unfillable stalls). Both waves run the same
// 3 MFMAs (pipe ~5% busy, duplication free); each wave runs gate math for
// HALF the dims (wave0: pi-dims j=0..3, wave1: j=4..7) -> per-wave transc
// 48->24/step. h-halves exchanged via double-buffered 8B/lane LDS exchange
// + one __syncthreads per step. Co-resident SIMD waves come from different
// blocks, so phases slide and stalls are mutually hidden.
//
// Everything else is R8 verbatim (absmax 7.8e-3): D[g][s]=W.h with
// mfma_f32_32x32x16_bf16; gx added in-MFMA (Agx k-slots 0..5 = 3-code gx
// hi+lo, B' one-hot from code); n-bias in C operand; W bf16 RNE; h bf16
// round-half-up pack; hidden-dim permutation pi(8h+j)=4h+(j&3)+8*(j>>2)
// makes each lane's D-rows == its B k-slots (in-lane B rebuild).

#define NBLK 1024  // 32768 / 32 samples per block

typedef __attribute__((ext_vector_type(8)))  short    short8;
typedef __attribute__((ext_vector_type(16))) float    floatx16;
typedef __attribute__((ext_vector_type(4)))  unsigned uintx4;

static __device__ __forceinline__ float fexp2(float x) { return __builtin_amdgcn_exp2f(x); }
static __device__ __forceinline__ float frcp(float x)  { return __builtin_amdgcn_rcpf(x); }
static __device__ __forceinline__ unsigned f2u(float f) { unsigned u; memcpy(&u, &f, 4); return u; }
static __device__ __forceinline__ unsigned short bfrne(float f) {
    union { __hip_bfloat16 b; unsigned short u; } cv; cv.b = __float2bfloat16(f); return cv.u;
}
static __device__ __forceinline__ float bf2f(unsigned short u) {
    unsigned v = ((unsigned)u) << 16; float f; memcpy(&f, &v, 4); return f;
}
// pack two floats as bf16 pair (a -> low16, b -> high16), round-half-up on bits
static __device__ __forceinline__ unsigned pkrnd(float a, float b) {
    unsigned ua = f2u(a) + 0x8000u;
    unsigned ub = f2u(b) + 0x8000u;
    return __builtin_amdgcn_perm(ub, ua, 0x07060302u);
}
static __device__ __forceinline__ float sel3f(int c, float a0, float a1, float a2) {
    return c == 0 ? a0 : (c == 1 ? a1 : a2);
}
static __device__ __forceinline__ unsigned sel3u(int c, unsigned a0, unsigned a1, unsigned a2) {
    return c == 0 ? a0 : (c == 1 ? a1 : a2);
}

__global__ __launch_bounds__(128) void gru_coop(
    const int* __restrict__ user_id,
    const int* __restrict__ launch_seq,
    const float* __restrict__ user_emb,
    const float* __restrict__ launch_emb,
    const float* __restrict__ W_ih,
    const float* __restrict__ W_hh,
    const float* __restrict__ b_ih,
    const float* __restrict__ b_hh,
    const float* __restrict__ fc_W,
    const float* __restrict__ fc_b,
    float* __restrict__ out)
{
    constexpr float L  = 1.4426950408889634f;   // log2(e)
    constexpr float L2 = 2.8853900817779268f;   // 2*log2(e)

    __shared__ float    gxlut[144];          // [(gate*3+code)*16 + dim]
    __shared__ unsigned xch[2][2][64][2];    // [buf][wid][lane][2 packed dwords]
    __shared__ float    redc[2][32];         // epilogue cross-wave reduce

    const int tid  = threadIdx.x;
    const int wid  = tid >> 6;     // wave id within block
    const int lane = tid & 63;
    const int n    = lane & 31;    // sample column (and A row m)
    const int half = lane >> 5;
    const int d1o  = 4 * half;
    const int dimo = d1o + 8 * wid;  // this wave's 4 actual dims: dimo..dimo+3
    const long long sampBase = (long long)blockIdx.x * 32;

    // ---- pack own sample's 64 codes into 4 dwords (2 bits each) ----
    unsigned pk[4];
    {
        const int* sp = launch_seq + (sampBase + n) * 64;
        #pragma unroll
        for (int w = 0; w < 4; ++w) {
            unsigned p = 0;
            #pragma unroll
            for (int j = 0; j < 4; ++j) {
                int4 v = ((const int4*)sp)[w * 4 + j];
                p |= ((unsigned)v.x & 3u) << (2 * (4 * j + 0));
                p |= ((unsigned)v.y & 3u) << (2 * (4 * j + 1));
                p |= ((unsigned)v.z & 3u) << (2 * (4 * j + 2));
                p |= ((unsigned)v.w & 3u) << (2 * (4 * j + 3));
            }
            pk[w] = p;
        }
    }

    // ---- gx LUT: 3 codes x 48 gates, pre-scaled ----
    for (int idx = tid; idx < 144; idx += 128) {
        int s = idx / 48, g = idx - s * 48;
        float dot = b_ih[g];
        #pragma unroll
        for (int k = 0; k < 16; ++k)
            dot = fmaf(W_ih[g * 16 + k], launch_emb[s * 16 + k], dot);
        int gate = g >> 4, dim = g & 15;
        gxlut[(gate * 3 + s) * 16 + dim] =
            (g < 32) ? (-L * (dot + b_hh[g])) : (L2 * dot);
    }

    // ---- weight A fragments (bf16 RNE, single plane), per (n, half) ----
    short8 Arz, An;
    {
        auto pack8 = [&](const float* w) {
            uintx4 hi;
            #pragma unroll
            for (int p = 0; p < 4; ++p)
                hi[p] = (unsigned)bfrne(w[2 * p]) | ((unsigned)bfrne(w[2 * p + 1]) << 16);
            return __builtin_bit_cast(short8, hi);
        };
        float w[8];
        const float* rowrz = W_hh + n * 16;            // rows 0..31 = [r;z]
        float4 a = *(const float4*)(rowrz + d1o);
        float4 b = *(const float4*)(rowrz + d1o + 8);
        w[0] = -L * a.x; w[1] = -L * a.y; w[2] = -L * a.z; w[3] = -L * a.w;
        w[4] = -L * b.x; w[5] = -L * b.y; w[6] = -L * b.z; w[7] = -L * b.w;
        Arz = pack8(w);
        if (n < 16) {
            const float* rown = W_hh + (32 + n) * 16;
            a = *(const float4*)(rown + d1o);
            b = *(const float4*)(rown + d1o + 8);
            w[0] = L2 * a.x; w[1] = L2 * a.y; w[2] = L2 * a.z; w[3] = L2 * a.w;
            w[4] = L2 * b.x; w[5] = L2 * b.y; w[6] = L2 * b.z; w[7] = L2 * b.w;
        } else {
            #pragma unroll
            for (int j = 0; j < 8; ++j) w[j] = 0.f;
        }
        An = pack8(w);
    }

    __syncthreads();   // gxlut visible

    // ---- Agx fragment: K-slots 0..2 = gx hi (codes 0..2), 3..5 = gx lo ----
    short8 Agx;
    {
        uintx4 d = {0u, 0u, 0u, 0u};
        if (half == 0) {
            const float* base = (n < 16) ? &gxlut[0] : &gxlut[48];
            int dim = n & 15;
            float g0 = base[0 * 16 + dim];
            float g1 = base[1 * 16 + dim];
            float g2 = base[2 * 16 + dim];
            unsigned short h0 = bfrne(g0), h1 = bfrne(g1), h2 = bfrne(g2);
            d[0] = (unsigned)h0 | ((unsigned)h1 << 16);
            d[1] = (unsigned)h2 | ((unsigned)bfrne(g0 - bf2f(h0)) << 16);
            d[2] = (unsigned)bfrne(g1 - bf2f(h1)) | ((unsigned)bfrne(g2 - bf2f(h2)) << 16);
        }
        Agx = __builtin_bit_cast(short8, d);
    }

    // one-hot constants for B' (zeroed on half==1 lanes, matching Agx rows)
    const unsigned khA = half ? 0u : 0x3F80u;        // bf16 1.0 in low16
    const unsigned khB = half ? 0u : 0x3F800000u;    // bf16 1.0 in high16

    // ---- n-gate C: bias in regs 0..7 (pi-dims), rest zero ----
    floatx16 Cn;
    #pragma unroll
    for (int i = 0; i < 16; ++i) Cn[i] = 0.f;
    {
        float4 a = *(const float4*)&b_hh[32 + d1o];
        float4 b = *(const float4*)&b_hh[32 + d1o + 8];
        Cn[0] = L2 * a.x; Cn[1] = L2 * a.y; Cn[2] = L2 * a.z; Cn[3] = L2 * a.w;
        Cn[4] = L2 * b.x; Cn[5] = L2 * b.y; Cn[6] = L2 * b.z; Cn[7] = L2 * b.w;
    }

    // ---- this wave's gx_n LUT (its 4 dims only) ----
    float gxn0[4], gxn1[4], gxn2[4];
    #pragma unroll
    for (int jj = 0; jj < 4; ++jj) {
        gxn0[jj] = gxlut[(6 + 0) * 16 + dimo + jj];
        gxn1[jj] = gxlut[(6 + 1) * 16 + dimo + jj];
        gxn2[jj] = gxlut[(6 + 2) * 16 + dimo + jj];
    }

    floatx16 CZ;
    #pragma unroll
    for (int i = 0; i < 16; ++i) CZ[i] = 0.f;

    float h4[4], pool4[4];
    #pragma unroll
    for (int jj = 0; jj < 4; ++jj) { h4[jj] = 0.f; pool4[jj] = 0.f; }
    short8 B = {0, 0, 0, 0, 0, 0, 0, 0};   // h0 = 0

    short8 Bp;
    {
        int c0 = (int)(pk[0] & 3u);
        uintx4 bp = { sel3u(c0, khA, khB, 0u),
                      sel3u(c0, khB, 0u, khA),
                      sel3u(c0, 0u, khA, khB), 0u };
        Bp = __builtin_bit_cast(short8, bp);
    }

    #pragma unroll
    for (int w = 0; w < 4; ++w) {
        unsigned cw  = pk[w];
        unsigned ncw = (pk[w] >> 2) | (w < 3 ? (pk[w + 1] << 30) : 0u);
        #pragma unroll 2
        for (int tt = 0; tt < 16; ++tt) {
            int c = (int)(cw & 3u);

            floatx16 t1  = __builtin_amdgcn_mfma_f32_32x32x16_bf16(Agx, Bp, CZ, 0, 0, 0);
            floatx16 dn  = __builtin_amdgcn_mfma_f32_32x32x16_bf16(An,  B, Cn, 0, 0, 0);
            floatx16 drz = __builtin_amdgcn_mfma_f32_32x32x16_bf16(Arz, B, t1, 0, 0, 0);

            // gate math for THIS wave's 4 dims (wid-uniform branch)
            auto gates = [&](int JO) {
                #pragma unroll
                for (int jj = 0; jj < 4; ++jj) {
                    float gn = sel3f(c, gxn0[jj], gxn1[jj], gxn2[jj]);
                    float r  = frcp(1.0f + fexp2(drz[JO + jj]));
                    float z  = frcp(1.0f + fexp2(drz[8 + JO + jj]));
                    float y  = fmaf(r, dn[JO + jj], gn);
                    float nn = fmaf(-2.0f, frcp(1.0f + fexp2(y)), 1.0f);
                    h4[jj] = fmaf(z, h4[jj] - nn, nn);
                    pool4[jj] += h4[jj];
                }
            };
            if (wid == 0) gates(0); else gates(4);

            // pack own half, exchange with twin wave (double-buffered)
            unsigned hp0 = pkrnd(h4[0], h4[1]);
            unsigned hp1 = pkrnd(h4[2], h4[3]);
            int buf = tt & 1;
            xch[buf][wid][lane][0] = hp0;
            xch[buf][wid][lane][1] = hp1;
            __syncthreads();
            unsigned tw0 = xch[buf][wid ^ 1][lane][0];
            unsigned tw1 = xch[buf][wid ^ 1][lane][1];

            uintx4 b;
            b[0] = wid ? tw0 : hp0;   // k-slots 0,1 (pi-dims 0..3)
            b[1] = wid ? tw1 : hp1;
            b[2] = wid ? hp0 : tw0;   // k-slots 2,3 (pi-dims 4..7)
            b[3] = wid ? hp1 : tw1;
            B = __builtin_bit_cast(short8, b);

            int cnx = (int)(ncw & 3u);
            uintx4 bp = { sel3u(cnx, khA, khB, 0u),
                          sel3u(cnx, khB, 0u, khA),
                          sel3u(cnx, 0u, khA, khB), 0u };
            Bp = __builtin_bit_cast(short8, bp);
            cw >>= 2;
            ncw >>= 2;
        }
    }

    // ---- epilogue: FC over [u, mean(h)], each wave covers its 4 dims ----
    float4 f1 = *(const float4*)&fc_W[dimo];
    float4 f2 = *(const float4*)&fc_W[16 + dimo];
    int uid = user_id[sampBase + n];
    float4 uu = *(const float4*)&user_emb[(long long)uid * 16 + dimo];
    const float inv64 = 1.0f / 64.0f;
    float val = f1.x * uu.x + f1.y * uu.y + f1.z * uu.z + f1.w * uu.w;
    val = fmaf(f2.x * inv64, pool4[0], val);
    val = fmaf(f2.y * inv64, pool4[1], val);
    val = fmaf(f2.z * inv64, pool4[2], val);
    val = fmaf(f2.w * inv64, pool4[3], val);
    val += __shfl_xor(val, 32);          // combine halves within wave
    if (half == 0) redc[wid][n] = val;   // per-wave partial
    __syncthreads();
    if (wid == 0 && half == 0)
        out[sampBase + n] = redc[0][n] + redc[1][n] + fc_b[0];
}

extern "C" void kernel_launch(void* const* d_in, const int* in_sizes, int n_in,
                              void* d_out, int out_size, void* d_ws, size_t ws_size,
                              hipStream_t stream) {
    const int*   user_id    = (const int*)d_in[0];
    const int*   launch_seq = (const int*)d_in[1];
    const float* user_emb   = (const float*)d_in[2];
    const float* launch_emb = (const float*)d_in[3];
    const float* W_ih       = (const float*)d_in[4];
    const float* W_hh       = (const float*)d_in[5];
    const float* b_ih       = (const float*)d_in[6];
    const float* b_hh       = (const float*)d_in[7];
    const float* fc_W       = (const float*)d_in[8];
    const float* fc_b       = (const float*)d_in[9];
    float* out = (float*)d_out;

    gru_coop<<<dim3(NBLK), dim3(128), 0, stream>>>(
        user_id, launch_seq, user_emb, launch_emb,
        W_ih, W_hh, b_ih, b_hh, fc_W, fc_b, out);
}

// Round 10
// 133.650 us; speedup vs baseline: 1.7482x; 1.7482x over previous
//
#include <hip/hip_runtime.h>
#include <hip/hip_bf16.h>
#include <string.h>

// GRU recommender, R10: B=32768, T=64, H=16, vocab=3.
// 2048 blocks x 1 wave x 16 samples -> 2048 waves = 2 FULLY INDEPENDENT
// waves/SIMD (R8 had 1 wave/SIMD => ~500cyc/step unfillable stall; R9's
// cross-wave sync convoyed; here waves never interact).
//
// mfma_f32_16x16x32_bf16, 3 per step (r,z,n gates):
//   D_g[dim m][sample n] ; C/D: col=lane&15=n, row=quad*4+reg=m.
//   A[m][k], B[k][n]: m/n=lane&15, k=8*quad+j.
//   A k=0..15: scaled W_hh columns (quads 0,1).
//   A k=16..21 (quad 2): gx LUT hi (codes 0..2) + lo; k=22..23: n-gate
//     bias hi+lo (zero for r/z; their b_hh is inside gx).
//   A k=24..31 (quad 3): zero (kills B garbage there).
//   B k=0..15: h (bf16, round-half-up); k=16..23: per-sample one-hot
//     (code-selected, +1.0 at k22/k23) so the MFMA adds gx/bias itself.
// B rebuild per step: lane (n,q) computed h[4q..4q+3][n]; its B k-slots
// 8q..8q+7 live in lanes (n,2q),(n,2q+1) -> 4 ds_bpermute of 2 packed
// dwords. No barriers, no LDS traffic (crossbar only).
// Gate transcendentals: 5/element (paired rcp: r,z share one rcp via
// 1/((1+er)(1+ez))), 20 per wave-step vs R8's 48.
// Numerics = R8 (absmax 7.8e-3): W bf16 RNE, h bf16 round-half-up,
// gx/bias hi+lo bf16 (~fp32), sigmoid=rcp(1+exp2(-L*x)),
// tanh = 1-2*rcp(1+exp2(2L*x)).

#define NBLK 2048  // 32768 / 16 samples per wave

typedef __attribute__((ext_vector_type(8))) short    short8;
typedef __attribute__((ext_vector_type(4))) float    floatx4;
typedef __attribute__((ext_vector_type(4))) unsigned uintx4;

static __device__ __forceinline__ float fexp2(float x) { return __builtin_amdgcn_exp2f(x); }
static __device__ __forceinline__ float frcp(float x)  { return __builtin_amdgcn_rcpf(x); }
static __device__ __forceinline__ unsigned f2u(float f) { unsigned u; memcpy(&u, &f, 4); return u; }
static __device__ __forceinline__ unsigned short bfrne(float f) {
    union { __hip_bfloat16 b; unsigned short u; } cv; cv.b = __float2bfloat16(f); return cv.u;
}
static __device__ __forceinline__ float bf2f(unsigned short u) {
    unsigned v = ((unsigned)u) << 16; float f; memcpy(&f, &v, 4); return f;
}
// pack two floats as bf16 pair (a -> low16, b -> high16), round-half-up
static __device__ __forceinline__ unsigned pkrnd(float a, float b) {
    unsigned ua = f2u(a) + 0x8000u;
    unsigned ub = f2u(b) + 0x8000u;
    return __builtin_amdgcn_perm(ub, ua, 0x07060302u);
}
static __device__ __forceinline__ float sel3f(int c, float a0, float a1, float a2) {
    return c == 0 ? a0 : (c == 1 ? a1 : a2);
}
static __device__ __forceinline__ unsigned sel3u(int c, unsigned a0, unsigned a1, unsigned a2) {
    return c == 0 ? a0 : (c == 1 ? a1 : a2);
}

__global__ __launch_bounds__(64) void gru16(
    const int* __restrict__ user_id,
    const int* __restrict__ launch_seq,
    const float* __restrict__ user_emb,
    const float* __restrict__ launch_emb,
    const float* __restrict__ W_ih,
    const float* __restrict__ W_hh,
    const float* __restrict__ b_ih,
    const float* __restrict__ b_hh,
    const float* __restrict__ fc_W,
    const float* __restrict__ fc_b,
    float* __restrict__ out)
{
    constexpr float L  = 1.4426950408889634f;   // log2(e)
    constexpr float L2 = 2.8853900817779268f;   // 2*log2(e)
    constexpr unsigned K_LO = 0x3F80u;          // bf16 1.0 in low16
    constexpr unsigned K_HI = 0x3F800000u;      // bf16 1.0 in high16

    __shared__ float gxlut[144];    // [(gate*3+code)*16 + dim]

    const int tid  = threadIdx.x;
    const int col  = tid & 15;     // sample n (B/C/D col); ALSO dim m for A rows
    const int quad = tid >> 4;
    const bool isq2 = (quad == 2);
    const long long sampBase = (long long)blockIdx.x * 16;

    // ---- pack sample col's 64 codes into 4 dwords (2 bits each) ----
    // (4-way redundant across quads; setup-only, L1/L2 absorb)
    unsigned pk[4];
    {
        const int* sp = launch_seq + (sampBase + col) * 64;
        #pragma unroll
        for (int w = 0; w < 4; ++w) {
            unsigned p = 0;
            #pragma unroll
            for (int j = 0; j < 4; ++j) {
                int4 v = ((const int4*)sp)[w * 4 + j];
                p |= ((unsigned)v.x & 3u) << (2 * (4 * j + 0));
                p |= ((unsigned)v.y & 3u) << (2 * (4 * j + 1));
                p |= ((unsigned)v.z & 3u) << (2 * (4 * j + 2));
                p |= ((unsigned)v.w & 3u) << (2 * (4 * j + 3));
            }
            pk[w] = p;
        }
    }

    // ---- gx LUT: 3 codes x 48 gates, pre-scaled ----
    for (int idx = tid; idx < 144; idx += 64) {
        int s = idx / 48, g = idx - s * 48;
        float dot = b_ih[g];
        #pragma unroll
        for (int k = 0; k < 16; ++k)
            dot = fmaf(W_ih[g * 16 + k], launch_emb[s * 16 + k], dot);
        int gate = g >> 4, dim = g & 15;
        gxlut[(gate * 3 + s) * 16 + dim] =
            (g < 32) ? (-L * (dot + b_hh[g])) : (L2 * dot);
    }

    __syncthreads();   // gxlut visible (A build + gxn LUT read it)

    // ---- A fragments per gate ----
    short8 Ar, Az, An_;
    {
        auto pack8 = [&](const float* w) {
            uintx4 hi;
            #pragma unroll
            for (int p = 0; p < 4; ++p)
                hi[p] = (unsigned)bfrne(w[2 * p]) | ((unsigned)bfrne(w[2 * p + 1]) << 16);
            return __builtin_bit_cast(short8, hi);
        };
        auto makeA = [&](int grow, float scale, const float* gx3, float bias, short8& A) {
            float w[8];
            #pragma unroll
            for (int j = 0; j < 8; ++j) w[j] = 0.f;
            if (quad < 2) {
                const float* row = W_hh + (grow + col) * 16 + quad * 8;
                float4 a = *(const float4*)row;
                float4 b = *(const float4*)(row + 4);
                w[0] = scale * a.x; w[1] = scale * a.y; w[2] = scale * a.z; w[3] = scale * a.w;
                w[4] = scale * b.x; w[5] = scale * b.y; w[6] = scale * b.z; w[7] = scale * b.w;
            } else if (quad == 2) {
                if (gx3) {
                    #pragma unroll
                    for (int c = 0; c < 3; ++c) {
                        float g = gx3[c * 16 + col];
                        w[c] = g;
                        w[3 + c] = g - bf2f(bfrne(g));   // lo residual
                    }
                } else {
                    w[6] = bias;
                    w[7] = bias - bf2f(bfrne(bias));     // bias lo residual
                }
            }
            A = pack8(w);
        };
        makeA(0,  -L, &gxlut[0],       0.f,               Ar);
        makeA(16, -L, &gxlut[3 * 16],  0.f,               Az);
        makeA(32,  L2, (const float*)0, L2 * b_hh[32 + col], An_);
    }

    // ---- per-lane gx_n LUT: codes 0..2 x this lane's 4 dims (4q..4q+3) ----
    floatx4 gn0 = *(const floatx4*)&gxlut[(6 + 0) * 16 + quad * 4];
    floatx4 gn1 = *(const floatx4*)&gxlut[(6 + 1) * 16 + quad * 4];
    floatx4 gn2 = *(const floatx4*)&gxlut[(6 + 2) * 16 + quad * 4];

    // ---- bpermute source addresses (loop-invariant) ----
    // lane (n,q) k-slots 8q..8q+7 <- dims computed by lanes (n,2q),(n,2q+1)
    const int a_lo = (col + 32 * (quad & 1)) * 4;   // q0->n, q1->n+32 (q2/3 don't-care)
    const int a_hi = a_lo + 64;                     // q0->n+16, q1->n+48

    floatx4 h    = {0.f, 0.f, 0.f, 0.f};
    floatx4 pool = {0.f, 0.f, 0.f, 0.f};
    const floatx4 CZ = {0.f, 0.f, 0.f, 0.f};

    // ---- initial B (h=0): zeros + quad-2 one-hot for code(t=0) ----
    short8 B;
    {
        int c0 = (int)(pk[0] & 3u);
        uintx4 b = {0u, 0u, 0u, 0u};
        if (isq2) {
            b[0] = sel3u(c0, K_LO, K_HI, 0u);
            b[1] = sel3u(c0, K_HI, 0u, K_LO);
            b[2] = sel3u(c0, 0u, K_LO, K_HI);
            b[3] = K_LO | K_HI;                    // k22=k23=1.0 (bias rows)
        }
        B = __builtin_bit_cast(short8, b);
    }

    #pragma unroll
    for (int w = 0; w < 4; ++w) {
        unsigned cw  = pk[w];
        unsigned ncw = (pk[w] >> 2) | (w < 3 ? (pk[w + 1] << 30) : 0u);
        #pragma unroll 4
        for (int tt = 0; tt < 16; ++tt) {
            int c = (int)(cw & 3u);

            floatx4 dr = __builtin_amdgcn_mfma_f32_16x16x32_bf16(Ar,  B, CZ, 0, 0, 0);
            floatx4 dz = __builtin_amdgcn_mfma_f32_16x16x32_bf16(Az,  B, CZ, 0, 0, 0);
            floatx4 dn = __builtin_amdgcn_mfma_f32_16x16x32_bf16(An_, B, CZ, 0, 0, 0);

            #pragma unroll
            for (int e = 0; e < 4; ++e) {
                float er = fexp2(dr[e]);
                float ez = fexp2(dz[e]);
                float t1 = 1.0f + er;
                float t2 = 1.0f + ez;
                float rp = frcp(t1 * t2);          // one rcp for both gates
                float r  = rp * t2;
                float z  = rp * t1;
                float gn = sel3f(c, gn0[e], gn1[e], gn2[e]);
                float y  = fmaf(r, dn[e], gn);
                float nn = fmaf(-2.0f, frcp(1.0f + fexp2(y)), 1.0f);
                h[e] = fmaf(z, h[e] - nn, nn);
                pool[e] += h[e];
            }

            // rebuild B for t+1: pack own 4 dims, pull 2 source lanes' packs
            unsigned hp0 = pkrnd(h[0], h[1]);
            unsigned hp1 = pkrnd(h[2], h[3]);
            int cn = (int)(ncw & 3u);
            uintx4 b;
            b[0] = (unsigned)__builtin_amdgcn_ds_bpermute(a_lo, (int)hp0);
            b[1] = (unsigned)__builtin_amdgcn_ds_bpermute(a_lo, (int)hp1);
            b[2] = (unsigned)__builtin_amdgcn_ds_bpermute(a_hi, (int)hp0);
            b[3] = (unsigned)__builtin_amdgcn_ds_bpermute(a_hi, (int)hp1);
            unsigned oh0 = sel3u(cn, K_LO, K_HI, 0u);
            unsigned oh1 = sel3u(cn, K_HI, 0u, K_LO);
            unsigned oh2 = sel3u(cn, 0u, K_LO, K_HI);
            b[0] = isq2 ? oh0 : b[0];
            b[1] = isq2 ? oh1 : b[1];
            b[2] = isq2 ? oh2 : b[2];
            b[3] = isq2 ? (K_LO | K_HI) : b[3];
            B = __builtin_bit_cast(short8, b);
            cw >>= 2;
            ncw >>= 2;
        }
    }

    // ---- epilogue: FC over [u, mean(h)]; lane covers dims 4q..4q+3 ----
    float4 f1 = *(const float4*)&fc_W[quad * 4];
    float4 f2 = *(const float4*)&fc_W[16 + quad * 4];
    int uid = user_id[sampBase + col];
    float4 uu = *(const float4*)&user_emb[(long long)uid * 16 + quad * 4];
    const float inv64 = 1.0f / 64.0f;
    float val = f1.x * uu.x + f1.y * uu.y + f1.z * uu.z + f1.w * uu.w;
    val = fmaf(f2.x * inv64, pool[0], val);
    val = fmaf(f2.y * inv64, pool[1], val);
    val = fmaf(f2.z * inv64, pool[2], val);
    val = fmaf(f2.w * inv64, pool[3], val);
    val += __shfl_xor(val, 16);
    val += __shfl_xor(val, 32);
    if (quad == 0) out[sampBase + col] = val + fc_b[0];
}

extern "C" void kernel_launch(void* const* d_in, const int* in_sizes, int n_in,
                              void* d_out, int out_size, void* d_ws, size_t ws_size,
                              hipStream_t stream) {
    const int*   user_id    = (const int*)d_in[0];
    const int*   launch_seq = (const int*)d_in[1];
    const float* user_emb   = (const float*)d_in[2];
    const float* launch_emb = (const float*)d_in[3];
    const float* W_ih       = (const float*)d_in[4];
    const float* W_hh       = (const float*)d_in[5];
    const float* b_ih       = (const float*)d_in[6];
    const float* b_hh       = (const float*)d_in[7];
    const float* fc_W       = (const float*)d_in[8];
    const float* fc_b       = (const float*)d_in[9];
    float* out = (float*)d_out;

    gru16<<<dim3(NBLK), dim3(64), 0, stream>>>(
        user_id, launch_seq, user_emb, launch_emb,
        W_ih, W_hh, b_ih, b_hh, fc_W, fc_b, out);
}

// Round 12
// 130.996 us; speedup vs baseline: 1.7836x; 1.0203x over previous
//
#include <hip/hip_runtime.h>
#include <hip/hip_bf16.h>
#include <string.h>

// GRU recommender, R11b: B=32768, T=64, H=16, vocab=3.
// 2048 blocks x 1 wave x 16 samples = 2 independent waves/SIMD.
//
// KEY: mfma_f32_16x16x16f16 (classic K=16 shape, 2-reg A/B).
//   A[m][k]: m=lane&15, k=4*quad+j ; B[k][n]: n=lane&15, k=4*quad+j.
//   D (m89 family): col=lane&15=n, row=quad*4+reg.
//   => lane (n,q) computes h'[4q..4q+3] of sample n (D rows) AND its B
//   k-slots are h[4q..4q+3] of sample n. IN-LANE B rebuild (2 cvt_pkrtz),
//   zero DS ops / zero waitcnt in the loop, at 16 samples/wave so we keep
//   2 waves/SIMD (R8's in-lane trick forced 1 wave/SIMD; R10's 2-wave
//   version paid a bpermute+lgkmcnt latency leg every step).
//
// K=16 fully used by h, so gx moves back to VALU: per-lane LUT (3 gates x
// 3 codes x my 4 dims = 36 VGPR) + sel3 cndmask per element; n-gate bias
// rides in the MFMA C operand (fp32, free). r/z b_hh is inside gxlut.
// h and W in FP16 (RTZ pack / RNE weights): ~8x finer than bf16 -> absmax
// should drop to ~1e-3. Gates: sigmoid=rcp(1+exp2(-L*x)) with r,z sharing
// one rcp via 1/((1+er)(1+ez)); tanh=1-2*rcp(1+exp2(L2*x)). 5 transc/elem.
//
// R11b fix: cvt_pkrtz returns __fp16x2 -> bit_cast to unsigned directly.

#define NBLK 2048  // 32768 / 16 samples per wave

typedef __attribute__((ext_vector_type(4))) _Float16 half4v;
typedef __attribute__((ext_vector_type(4))) float    floatx4;
typedef __attribute__((ext_vector_type(2))) unsigned uintx2;

static __device__ __forceinline__ float fexp2(float x) { return __builtin_amdgcn_exp2f(x); }
static __device__ __forceinline__ float frcp(float x)  { return __builtin_amdgcn_rcpf(x); }
static __device__ __forceinline__ unsigned pkh2(float a, float b) {
    return __builtin_bit_cast(unsigned, __builtin_amdgcn_cvt_pkrtz(a, b));
}
static __device__ __forceinline__ float sel3f(int c, float a0, float a1, float a2) {
    return c == 0 ? a0 : (c == 1 ? a1 : a2);
}

__global__ __launch_bounds__(64) void gru16h(
    const int* __restrict__ user_id,
    const int* __restrict__ launch_seq,
    const float* __restrict__ user_emb,
    const float* __restrict__ launch_emb,
    const float* __restrict__ W_ih,
    const float* __restrict__ W_hh,
    const float* __restrict__ b_ih,
    const float* __restrict__ b_hh,
    const float* __restrict__ fc_W,
    const float* __restrict__ fc_b,
    float* __restrict__ out)
{
    constexpr float L  = 1.4426950408889634f;   // log2(e)
    constexpr float L2 = 2.8853900817779268f;   // 2*log2(e)

    __shared__ float gxlut[144];    // [(gate*3+code)*16 + dim]

    const int tid  = threadIdx.x;
    const int col  = tid & 15;     // sample n ; also A row m (gate dim)
    const int quad = tid >> 4;
    const long long sampBase = (long long)blockIdx.x * 16;

    // ---- pack sample col's 64 codes into 4 dwords (2 bits each) ----
    unsigned pk[4];
    {
        const int* sp = launch_seq + (sampBase + col) * 64;
        #pragma unroll
        for (int w = 0; w < 4; ++w) {
            unsigned p = 0;
            #pragma unroll
            for (int j = 0; j < 4; ++j) {
                int4 v = ((const int4*)sp)[w * 4 + j];
                p |= ((unsigned)v.x & 3u) << (2 * (4 * j + 0));
                p |= ((unsigned)v.y & 3u) << (2 * (4 * j + 1));
                p |= ((unsigned)v.z & 3u) << (2 * (4 * j + 2));
                p |= ((unsigned)v.w & 3u) << (2 * (4 * j + 3));
            }
            pk[w] = p;
        }
    }

    // ---- gx LUT: 3 codes x 48 gates, pre-scaled ----
    for (int idx = tid; idx < 144; idx += 64) {
        int s = idx / 48, g = idx - s * 48;
        float dot = b_ih[g];
        #pragma unroll
        for (int k = 0; k < 16; ++k)
            dot = fmaf(W_ih[g * 16 + k], launch_emb[s * 16 + k], dot);
        int gate = g >> 4, dim = g & 15;
        gxlut[(gate * 3 + s) * 16 + dim] =
            (g < 32) ? (-L * (dot + b_hh[g])) : (L2 * dot);
    }

    // ---- A fragments: W_hh row `col`, k-cols 4q..4q+3, fp16 RNE ----
    half4v Ar, Az, An_;
    {
        auto makeA = [&](int grow, float scale) {
            const float* row = W_hh + (grow + col) * 16 + quad * 4;
            float4 a = *(const float4*)row;
            half4v r;
            r[0] = (_Float16)(scale * a.x);
            r[1] = (_Float16)(scale * a.y);
            r[2] = (_Float16)(scale * a.z);
            r[3] = (_Float16)(scale * a.w);
            return r;
        };
        Ar  = makeA(0,  -L);
        Az  = makeA(16, -L);
        An_ = makeA(32,  L2);
    }

    // ---- n-gate bias in C operand (rows 4q..4q+3 of every column) ----
    floatx4 Cn;
    {
        float4 b = *(const float4*)&b_hh[32 + quad * 4];
        Cn = floatx4{L2 * b.x, L2 * b.y, L2 * b.z, L2 * b.w};
    }

    __syncthreads();   // gxlut visible

    // ---- per-lane gx LUT: 3 gates x 3 codes x my 4 dims (36 VGPR) ----
    floatx4 gr0 = *(const floatx4*)&gxlut[(0 * 3 + 0) * 16 + quad * 4];
    floatx4 gr1 = *(const floatx4*)&gxlut[(0 * 3 + 1) * 16 + quad * 4];
    floatx4 gr2 = *(const floatx4*)&gxlut[(0 * 3 + 2) * 16 + quad * 4];
    floatx4 gz0 = *(const floatx4*)&gxlut[(1 * 3 + 0) * 16 + quad * 4];
    floatx4 gz1 = *(const floatx4*)&gxlut[(1 * 3 + 1) * 16 + quad * 4];
    floatx4 gz2 = *(const floatx4*)&gxlut[(1 * 3 + 2) * 16 + quad * 4];
    floatx4 gn0 = *(const floatx4*)&gxlut[(2 * 3 + 0) * 16 + quad * 4];
    floatx4 gn1 = *(const floatx4*)&gxlut[(2 * 3 + 1) * 16 + quad * 4];
    floatx4 gn2 = *(const floatx4*)&gxlut[(2 * 3 + 2) * 16 + quad * 4];

    floatx4 h    = {0.f, 0.f, 0.f, 0.f};
    floatx4 pool = {0.f, 0.f, 0.f, 0.f};
    const floatx4 CZ = {0.f, 0.f, 0.f, 0.f};
    uintx2 Bb = {0u, 0u};   // h0 = 0 (packed fp16 pairs)

    #pragma unroll
    for (int w = 0; w < 4; ++w) {
        unsigned cw = pk[w];
        #pragma unroll 4
        for (int tt = 0; tt < 16; ++tt) {
            int c = (int)(cw & 3u);
            cw >>= 2;

            half4v B = __builtin_bit_cast(half4v, Bb);
            floatx4 dr = __builtin_amdgcn_mfma_f32_16x16x16f16(Ar,  B, CZ, 0, 0, 0);
            floatx4 dz = __builtin_amdgcn_mfma_f32_16x16x16f16(Az,  B, CZ, 0, 0, 0);
            floatx4 dn = __builtin_amdgcn_mfma_f32_16x16x16f16(An_, B, Cn, 0, 0, 0);

            #pragma unroll
            for (int e = 0; e < 4; ++e) {
                float ar = dr[e] + sel3f(c, gr0[e], gr1[e], gr2[e]);
                float az = dz[e] + sel3f(c, gz0[e], gz1[e], gz2[e]);
                float gn = sel3f(c, gn0[e], gn1[e], gn2[e]);
                float er = fexp2(ar);
                float ez = fexp2(az);
                float t1 = 1.0f + er;
                float t2 = 1.0f + ez;
                float rp = frcp(t1 * t2);          // one rcp serves r and z
                float r  = rp * t2;
                float z  = rp * t1;
                float y  = fmaf(r, dn[e], gn);
                float nn = fmaf(-2.0f, frcp(1.0f + fexp2(y)), 1.0f);
                h[e] = fmaf(z, h[e] - nn, nn);
                pool[e] += h[e];
            }

            // in-lane B rebuild: this lane's 4 h-dims ARE its 4 B k-slots
            Bb[0] = pkh2(h[0], h[1]);
            Bb[1] = pkh2(h[2], h[3]);
        }
    }

    // ---- epilogue: FC over [u, mean(h)]; lane covers dims 4q..4q+3 ----
    float4 f1 = *(const float4*)&fc_W[quad * 4];
    float4 f2 = *(const float4*)&fc_W[16 + quad * 4];
    int uid = user_id[sampBase + col];
    float4 uu = *(const float4*)&user_emb[(long long)uid * 16 + quad * 4];
    const float inv64 = 1.0f / 64.0f;
    float val = f1.x * uu.x + f1.y * uu.y + f1.z * uu.z + f1.w * uu.w;
    val = fmaf(f2.x * inv64, pool[0], val);
    val = fmaf(f2.y * inv64, pool[1], val);
    val = fmaf(f2.z * inv64, pool[2], val);
    val = fmaf(f2.w * inv64, pool[3], val);
    val += __shfl_xor(val, 16);
    val += __shfl_xor(val, 32);
    if (quad == 0) out[sampBase + col] = val + fc_b[0];
}

extern "C" void kernel_launch(void* const* d_in, const int* in_sizes, int n_in,
                              void* d_out, int out_size, void* d_ws, size_t ws_size,
                              hipStream_t stream) {
    const int*   user_id    = (const int*)d_in[0];
    const int*   launch_seq = (const int*)d_in[1];
    const float* user_emb   = (const float*)d_in[2];
    const float* launch_emb = (const float*)d_in[3];
    const float* W_ih       = (const float*)d_in[4];
    const float* W_hh       = (const float*)d_in[5];
    const float* b_ih       = (const float*)d_in[6];
    const float* b_hh       = (const float*)d_in[7];
    const float* fc_W       = (const float*)d_in[8];
    const float* fc_b       = (const float*)d_in[9];
    float* out = (float*)d_out;

    gru16h<<<dim3(NBLK), dim3(64), 0, stream>>>(
        user_id, launch_seq, user_emb, launch_emb,
        W_ih, W_hh, b_ih, b_hh, fc_W, fc_b, out);
}